// Round 1
// baseline (987.769 us; speedup 1.0000x reference)
//
#include <hip/hip_runtime.h>

// DigitCapsules dynamic routing, fully fused: one block per batch element.
// B=256, C=10, I=1152, DI=8, DO=16, 3 routing iterations.
//
// Design:
//  - grid = 256 blocks (one per b), 256 threads/block.
//  - thread t owns capsules i = t + 256*j (j=0..4; 4 or 5 each).
//  - x[b,i,:] held in registers (float4 x2 per i).
//  - blog[i][c] held in registers (<=50 VGPRs) -> softmax over classes is
//    thread-local, no cross-thread comms needed for routing weights.
//  - u_hat recomputed from W each phase (W streams through L2/L3; only
//    ~15 MB ever fetched from HBM). 5 W-sweeps total:
//    agreement (it=1,2) + weighted-sum (it=0,1,2).
//  - s reduced across the block via wave shuffles + tiny LDS scratch;
//    squash done by threads 0..159; v broadcast via 640 B of LDS.
//  - no workspace, no atomics, no multi-kernel, graph-capture safe.

#define NBATCH 256
#define NCLS   10
#define NCAPS  1152
#define KDI    8
#define KDO    16
#define NIT    3

__global__ __launch_bounds__(256, 2)
void caps_routing(const float* __restrict__ x,   // [B, I, DI]
                  const float* __restrict__ W,   // [C, I, 1, DO, DI]
                  float* __restrict__ out)       // [B, C, 1, DO]
{
    const int b    = blockIdx.x;
    const int t    = threadIdx.x;
    const int lane = t & 63;
    const int wave = t >> 6;

    __shared__ float v_prev[NCLS * KDO];        // v from previous iteration
    __shared__ float red[NCLS * 4 * KDO];       // per-wave partial s

    // ---- load x[b, i, :] for my i's into registers (coalesced float4) ----
    float4 xr[5][2];
    const float4* x4 = reinterpret_cast<const float4*>(x + (size_t)b * NCAPS * KDI);
    #pragma unroll
    for (int j = 0; j < 5; ++j) {
        int i = t + 256 * j;
        if (i < NCAPS) {
            xr[j][0] = x4[2 * i];
            xr[j][1] = x4[2 * i + 1];
        }
    }

    // ---- routing logits, thread-local ----
    float blog[5][NCLS];
    #pragma unroll
    for (int j = 0; j < 5; ++j)
        #pragma unroll
        for (int c = 0; c < NCLS; ++c)
            blog[j][c] = 0.f;

    const float4* W4 = reinterpret_cast<const float4*>(W);

    for (int it = 0; it < NIT; ++it) {
        // ---- Phase A: blog[i][c] += <u_hat[c,i,:], v_prev[c,:]> ----
        if (it > 0) {
            for (int c = 0; c < NCLS; ++c) {
                float vp[KDO];
                #pragma unroll
                for (int d = 0; d < KDO; ++d)
                    vp[d] = v_prev[c * KDO + d];   // LDS broadcast

                #pragma unroll
                for (int j = 0; j < 5; ++j) {
                    int i = t + 256 * j;
                    if (i < NCAPS) {
                        size_t wb = (size_t)(c * NCAPS + i) * 32;  // float4 units
                        float a = 0.f;
                        #pragma unroll
                        for (int d = 0; d < KDO; ++d) {
                            float4 w0 = W4[wb + 2 * d];
                            float4 w1 = W4[wb + 2 * d + 1];
                            float u = w0.x * xr[j][0].x + w0.y * xr[j][0].y
                                    + w0.z * xr[j][0].z + w0.w * xr[j][0].w
                                    + w1.x * xr[j][1].x + w1.y * xr[j][1].y
                                    + w1.z * xr[j][1].z + w1.w * xr[j][1].w;
                            a += u * vp[d];
                        }
                        blog[j][c] += a;
                    }
                }
            }
        }

        // ---- Phase B: softmax over classes (thread-local) ----
        float sm[5], sid[5];
        #pragma unroll
        for (int j = 0; j < 5; ++j) {
            int i = t + 256 * j;
            if (i < NCAPS) {
                float m = blog[j][0];
                #pragma unroll
                for (int c = 1; c < NCLS; ++c) m = fmaxf(m, blog[j][c]);
                float den = 0.f;
                #pragma unroll
                for (int c = 0; c < NCLS; ++c) den += __expf(blog[j][c] - m);
                sm[j]  = m;
                sid[j] = 1.f / den;
            }
        }

        // ---- Phase C: s[c,:] = sum_i w[c,i] * u_hat[c,i,:] ----
        for (int c = 0; c < NCLS; ++c) {
            float acc[KDO];
            #pragma unroll
            for (int d = 0; d < KDO; ++d) acc[d] = 0.f;

            #pragma unroll
            for (int j = 0; j < 5; ++j) {
                int i = t + 256 * j;
                if (i < NCAPS) {
                    float w = __expf(blog[j][c] - sm[j]) * sid[j];
                    size_t wb = (size_t)(c * NCAPS + i) * 32;
                    #pragma unroll
                    for (int d = 0; d < KDO; ++d) {
                        float4 w0 = W4[wb + 2 * d];
                        float4 w1 = W4[wb + 2 * d + 1];
                        float u = w0.x * xr[j][0].x + w0.y * xr[j][0].y
                                + w0.z * xr[j][0].z + w0.w * xr[j][0].w
                                + w1.x * xr[j][1].x + w1.y * xr[j][1].y
                                + w1.z * xr[j][1].z + w1.w * xr[j][1].w;
                        acc[d] += w * u;
                    }
                }
            }

            // block-reduce acc[d] over 256 threads: wave shuffle, then LDS
            #pragma unroll
            for (int d = 0; d < KDO; ++d) {
                float v = acc[d];
                v += __shfl_xor(v, 32, 64);
                v += __shfl_xor(v, 16, 64);
                v += __shfl_xor(v,  8, 64);
                v += __shfl_xor(v,  4, 64);
                v += __shfl_xor(v,  2, 64);
                v += __shfl_xor(v,  1, 64);
                if (lane == 0) red[(c * 4 + wave) * KDO + d] = v;
            }
        }
        __syncthreads();

        // ---- squash + v broadcast: threads 0..159 (c = t/16, d = t%16) ----
        if (t < NCLS * KDO) {
            int c = t >> 4;
            int d = t & 15;
            float s = red[(c * 4 + 0) * KDO + d] + red[(c * 4 + 1) * KDO + d]
                    + red[(c * 4 + 2) * KDO + d] + red[(c * 4 + 3) * KDO + d];
            float nsq = s * s;
            nsq += __shfl_xor(nsq, 8, 16);
            nsq += __shfl_xor(nsq, 4, 16);
            nsq += __shfl_xor(nsq, 2, 16);
            nsq += __shfl_xor(nsq, 1, 16);
            float scale = sqrtf(nsq) / (1.f + nsq);   // (nsq/(1+nsq))/sqrt(nsq)
            float vv = s * scale;
            v_prev[t] = vv;
            if (it == NIT - 1)
                out[(size_t)b * NCLS * KDO + t] = vv;
        }
        __syncthreads();
    }
}

extern "C" void kernel_launch(void* const* d_in, const int* in_sizes, int n_in,
                              void* d_out, int out_size, void* d_ws, size_t ws_size,
                              hipStream_t stream) {
    const float* x = (const float*)d_in[0];   // [256, 1152, 8] fp32
    const float* W = (const float*)d_in[1];   // [10, 1152, 1, 16, 8] fp32
    float* out = (float*)d_out;               // [256, 10, 1, 16] fp32
    (void)d_ws; (void)ws_size; (void)in_sizes; (void)n_in; (void)out_size;
    caps_routing<<<dim3(NBATCH), dim3(256), 0, stream>>>(x, W, out);
}